// Round 1
// baseline (86.973 us; speedup 1.0000x reference)
//
#include <hip/hip_runtime.h>
#include <hip/hip_bf16.h>

// Problem constants (from reference setup)
#define BN 64
#define HH 384
#define WW 384
#define NP 96
#define NS 96

__global__ __launch_bounds__(256) void lens_kernel(
    const float* __restrict__ lens_grid,      // [1,H,W,2]
    const float* __restrict__ pemd_params,    // [NP,6]
    const float* __restrict__ precomp_params, // [NP,4]
    const float* __restrict__ source_params,  // [NS,4]
    const int*   __restrict__ batch_idx,      // [B]
    const int*   __restrict__ pemd_sys_idx,   // [NP]
    const int*   __restrict__ precomp_map,    // [4]
    const int*   __restrict__ source_sys_idx, // [NS]
    float*       __restrict__ out)            // [B,H,W]
{
    // Per-batch compacted component lists in LDS
    __shared__ float sPx0[NP], sPy0[NP], sPq[NP], sPc[NP], sPs[NP], sPe[NP], sPb[NP];
    __shared__ float sSx0[NS], sSy0[NS], sSk[NS], sSa[NS];
    __shared__ unsigned char fP[NP], fS[NS];
    __shared__ int cntP, cntS;

    const int tid = threadIdx.x;
    const int b   = blockIdx.y;

    // ---- phase 1: membership flags (component n belongs to batch slot b?) ----
    if (tid < NP) {
        int sys = pemd_sys_idx[tid];
        int nb = -1;
        for (int k = 0; k < BN; ++k) { if (batch_idx[k] == sys) { nb = k; break; } }
        fP[tid] = (nb == b) ? 1 : 0;
    }
    if (tid >= 128 && tid < 128 + NS) {
        int t = tid - 128;
        int sys = source_sys_idx[t];
        int nb = -1;
        for (int k = 0; k < BN; ++k) { if (batch_idx[k] == sys) { nb = k; break; } }
        fS[t] = (nb == b) ? 1 : 0;
    }
    __syncthreads();

    // ---- phase 2: order-preserving compaction + per-component precompute ----
    if (tid < NP && fP[tid]) {
        int pos = 0;
        for (int k = 0; k < tid; ++k) pos += fP[k];
        const float* p = pemd_params + tid * 6;
        float x0 = p[0], y0 = p[1], q = p[2], phi = p[3], thE = p[4];
        float s, c;
        __sincosf(phi, &s, &c);
        float e = sqrtf(fmaxf(1.0f - q * q, 1e-8f));
        int pm0 = precomp_map[0];
        float scale = precomp_params[tid * 4 + pm0];
        float bco = thE * scale * q / e;
        sPx0[pos] = x0; sPy0[pos] = y0; sPq[pos] = q;
        sPc[pos] = c;   sPs[pos] = s;   sPe[pos] = e; sPb[pos] = bco;
    }
    if (tid == 96) { int n = 0; for (int k = 0; k < NP; ++k) n += fP[k]; cntP = n; }
    if (tid >= 128 && tid < 128 + NS && fS[tid - 128]) {
        int t = tid - 128;
        int pos = 0;
        for (int k = 0; k < t; ++k) pos += fS[k];
        const float* p = source_params + t * 4;
        float x0 = p[0], y0 = p[1], sg = p[2], amp = p[3];
        sSx0[pos] = x0; sSy0[pos] = y0;
        sSk[pos] = -0.5f / (sg * sg); sSa[pos] = amp;
    }
    if (tid == 224) { int n = 0; for (int k = 0; k < NS; ++k) n += fS[k]; cntS = n; }
    __syncthreads();

    const int nP = cntP;
    const int nS = cntS;

    // ---- phase 3: 4 pixels per thread ----
    const int po = blockIdx.x * 1024 + tid * 4;   // pixel offset within one image
    const float* gp = lens_grid + (size_t)po * 2; // interleaved x,y
    float4 gA = *(const float4*)gp;
    float4 gB = *(const float4*)(gp + 4);
    float gx[4] = { gA.x, gA.z, gB.x, gB.z };
    float gy[4] = { gA.y, gA.w, gB.y, gB.w };
    float dx[4] = { 0.f, 0.f, 0.f, 0.f };
    float dy[4] = { 0.f, 0.f, 0.f, 0.f };

    for (int n = 0; n < nP; ++n) {
        float x0 = sPx0[n], y0 = sPy0[n], q = sPq[n];
        float c = sPc[n], s = sPs[n], e = sPe[n], bco = sPb[n];
        #pragma unroll
        for (int u = 0; u < 4; ++u) {
            float x  = gx[u] - x0;
            float y  = gy[u] - y0;
            float xr = c * x + s * y;
            float yr = c * y - s * x;
            float psi = sqrtf(q * q * xr * xr + yr * yr) + 1e-12f;
            float rp = __fdividef(1.0f, psi);
            float tx = e * xr * rp;
            float ty = e * yr * rp;
            float ax = bco * atanf(tx);
            float tc = fminf(fmaxf(ty, -1.0f + 1e-6f), 1.0f - 1e-6f);
            float ay = bco * 0.5f * __logf(__fdividef(1.0f + tc, 1.0f - tc));
            dx[u] += c * ax - s * ay;
            dy[u] += s * ax + c * ay;
        }
    }

    float br[4] = { 0.f, 0.f, 0.f, 0.f };
    for (int n = 0; n < nS; ++n) {
        float x0 = sSx0[n], y0 = sSy0[n], k2 = sSk[n], amp = sSa[n];
        #pragma unroll
        for (int u = 0; u < 4; ++u) {
            float sx = gx[u] - dx[u] - x0;
            float sy = gy[u] - dy[u] - y0;
            br[u] += amp * __expf(k2 * (sx * sx + sy * sy));
        }
    }

    float4 o = { br[0], br[1], br[2], br[3] };
    *(float4*)(out + (size_t)b * (HH * WW) + po) = o;
}

extern "C" void kernel_launch(void* const* d_in, const int* in_sizes, int n_in,
                              void* d_out, int out_size, void* d_ws, size_t ws_size,
                              hipStream_t stream) {
    const float* lens_grid      = (const float*)d_in[0];
    const float* pemd_params    = (const float*)d_in[1];
    const float* precomp_params = (const float*)d_in[2];
    const float* source_params  = (const float*)d_in[3];
    const int*   batch_idx      = (const int*)d_in[4];
    const int*   pemd_sys_idx   = (const int*)d_in[5];
    // d_in[6] = precomp_sys_idx (unused by the reference computation)
    const int*   precomp_map    = (const int*)d_in[7];
    const int*   source_sys_idx = (const int*)d_in[8];
    float* out = (float*)d_out;

    dim3 grid((HH * WW) / 1024, BN, 1);   // 144 x 64 blocks; 256 thr x 4 px = 1024 px/block
    lens_kernel<<<grid, 256, 0, stream>>>(lens_grid, pemd_params, precomp_params,
                                          source_params, batch_idx, pemd_sys_idx,
                                          precomp_map, source_sys_idx, out);
}

// Round 2
// 50.617 us; speedup vs baseline: 1.7182x; 1.7182x over previous
//
#include <hip/hip_runtime.h>

#define BN 64
#define HH 384
#define WW 384
#define NP 96
#define NS 96
#define NPIX (HH * WW)

// d_ws layout:
//   bytes [0, 1024):    int startP[64], cntP[64], startS[64], cntS[64]
//   bytes [1024, 4096): float PP[96][8]  (x0,y0,q2,cos | sin,e,b,b/2)
//   bytes [4096, 5632): float SP[96][4]  (x0,y0,-0.5/sig^2,amp)

__device__ __forceinline__ float fast_atan(float t) {
    float a = __builtin_fabsf(t);
    float r = __builtin_amdgcn_rcpf(a);
    bool big = a > 1.0f;
    float u = big ? r : a;
    float u2 = u * u;
    float p = -0.0117212f;
    p = fmaf(p, u2, 0.05265332f);
    p = fmaf(p, u2, -0.11643287f);
    p = fmaf(p, u2, 0.19354346f);
    p = fmaf(p, u2, -0.33262347f);
    p = fmaf(p, u2, 0.99997726f);
    p = p * u;
    p = big ? (1.57079632679f - p) : p;
    return copysignf(p, t);
}

__global__ void lens_setup(
    const float* __restrict__ pemd_params,    // [NP,6]
    const float* __restrict__ precomp_params, // [NP,4]
    const float* __restrict__ source_params,  // [NS,4]
    const int*   __restrict__ batch_idx,      // [BN]
    const int*   __restrict__ pemd_sys_idx,   // [NP]
    const int*   __restrict__ precomp_map,    // [4]
    const int*   __restrict__ source_sys_idx, // [NS]
    int* __restrict__ ws_i, float* __restrict__ wsP, float* __restrict__ wsS)
{
    __shared__ int sBI[BN];
    __shared__ int nbP[NP], nbS[NS], posP[NP], posS[NS];
    __shared__ int startPb[BN], startSb[BN], cntb[2 * BN];
    const int t = threadIdx.x;  // 128 threads

    if (t < BN) sBI[t] = batch_idx[t];
    __syncthreads();

    if (t < NP) {
        int sys = pemd_sys_idx[t];
        int nb = -1;
        for (int k = 0; k < BN; ++k) if (sBI[k] == sys) { nb = k; break; }
        nbP[t] = nb;
        int sys2 = source_sys_idx[t];
        int nb2 = -1;
        for (int k = 0; k < BN; ++k) if (sBI[k] == sys2) { nb2 = k; break; }
        nbS[t] = nb2;
    }
    __syncthreads();

    if (t == 0) {  // stable counting sort, PEMD
        for (int b = 0; b < BN; ++b) cntb[b] = 0;
        for (int n = 0; n < NP; ++n) {
            int nb = nbP[n];
            posP[n] = (nb >= 0) ? cntb[nb]++ : -1;
        }
        int off = 0;
        for (int b = 0; b < BN; ++b) {
            startPb[b] = off; ws_i[b] = off; ws_i[64 + b] = cntb[b]; off += cntb[b];
        }
    }
    if (t == 64) {  // stable counting sort, sources
        for (int b = 0; b < BN; ++b) cntb[BN + b] = 0;
        for (int n = 0; n < NS; ++n) {
            int nb = nbS[n];
            posS[n] = (nb >= 0) ? cntb[BN + nb]++ : -1;
        }
        int off = 0;
        for (int b = 0; b < BN; ++b) {
            startSb[b] = off; ws_i[128 + b] = off; ws_i[192 + b] = cntb[BN + b]; off += cntb[BN + b];
        }
    }
    __syncthreads();

    if (t < NP) {
        int nb = nbP[t];
        if (nb >= 0) {
            const float* p = pemd_params + t * 6;
            float x0 = p[0], y0 = p[1], q = p[2], phi = p[3], thE = p[4];
            float sn, cs;
            __sincosf(phi, &sn, &cs);
            float q2 = q * q;
            float e = sqrtf(fmaxf(1.0f - q2, 1e-8f));
            float scale = precomp_params[t * 4 + precomp_map[0]];
            float bco = thE * scale * q / e;
            int gp = startPb[nb] + posP[t];
            float4* w = (float4*)wsP;
            w[gp * 2]     = make_float4(x0, y0, q2, cs);
            w[gp * 2 + 1] = make_float4(sn, e, bco, 0.5f * bco);
        }
        int nb2 = nbS[t];
        if (nb2 >= 0) {
            const float* p = source_params + t * 4;
            float sg = p[2];
            int gs = startSb[nb2] + posS[t];
            ((float4*)wsS)[gs] = make_float4(p[0], p[1], -0.5f / (sg * sg), p[3]);
        }
    }
}

__global__ __launch_bounds__(256) void lens_main(
    const float* __restrict__ grid,   // [H*W*2] interleaved
    const int*   __restrict__ ws_i,
    const float* __restrict__ wsP,
    const float* __restrict__ wsS,
    float*       __restrict__ out)    // [B,H,W]
{
    const int b = blockIdx.y;
    const int startP = ws_i[b],       nP = ws_i[64 + b];
    const int startS = ws_i[128 + b], nS = ws_i[192 + b];

    const int po = blockIdx.x * 2048 + threadIdx.x * 8;  // 8 px/thread
    const float4* g4 = (const float4*)(grid + (size_t)po * 2);
    float gx[8], gy[8];
    float dx[8] = {0, 0, 0, 0, 0, 0, 0, 0};
    float dy[8] = {0, 0, 0, 0, 0, 0, 0, 0};
    #pragma unroll
    for (int u = 0; u < 4; ++u) {
        float4 v = g4[u];
        gx[2 * u] = v.x; gy[2 * u] = v.y;
        gx[2 * u + 1] = v.z; gy[2 * u + 1] = v.w;
    }

    const float4* P4 = (const float4*)wsP;
    for (int n = 0; n < nP; ++n) {
        float4 p0 = P4[(startP + n) * 2];
        float4 p1 = P4[(startP + n) * 2 + 1];
        float x0 = p0.x, y0 = p0.y, q2 = p0.z, cs = p0.w;
        float sn = p1.x, e = p1.y, bco = p1.z, hb = p1.w;
        #pragma unroll
        for (int u = 0; u < 8; ++u) {
            float x = gx[u] - x0;
            float y = gy[u] - y0;
            float xr = fmaf(cs, x, sn * y);
            float yr = fmaf(cs, y, -(sn * x));
            float h = fmaf(q2 * xr, xr, yr * yr);
            float rp = __builtin_amdgcn_rsqf(h + 1e-24f);
            float tx = e * xr * rp;
            float ty = e * yr * rp;
            float ax = bco * fast_atan(tx);
            float tc = fminf(fmaxf(ty, -0.999999f), 0.999999f);
            float L = __logf((1.0f + tc) * __builtin_amdgcn_rcpf(1.0f - tc));
            float ay = hb * L;
            dx[u] = fmaf(cs, ax, dx[u]);
            dx[u] = fmaf(-sn, ay, dx[u]);
            dy[u] = fmaf(sn, ax, dy[u]);
            dy[u] = fmaf(cs, ay, dy[u]);
        }
    }

    float br[8] = {0, 0, 0, 0, 0, 0, 0, 0};
    const float4* S4 = (const float4*)wsS;
    for (int n = 0; n < nS; ++n) {
        float4 sp = S4[startS + n];
        #pragma unroll
        for (int u = 0; u < 8; ++u) {
            float sx = gx[u] - dx[u] - sp.x;
            float sy = gy[u] - dy[u] - sp.y;
            float r2 = fmaf(sx, sx, sy * sy);
            br[u] = fmaf(sp.w, __expf(sp.z * r2), br[u]);
        }
    }

    float* op = out + (size_t)b * NPIX + po;
    ((float4*)op)[0] = make_float4(br[0], br[1], br[2], br[3]);
    ((float4*)op)[1] = make_float4(br[4], br[5], br[6], br[7]);
}

extern "C" void kernel_launch(void* const* d_in, const int* in_sizes, int n_in,
                              void* d_out, int out_size, void* d_ws, size_t ws_size,
                              hipStream_t stream) {
    const float* lens_grid      = (const float*)d_in[0];
    const float* pemd_params    = (const float*)d_in[1];
    const float* precomp_params = (const float*)d_in[2];
    const float* source_params  = (const float*)d_in[3];
    const int*   batch_idx      = (const int*)d_in[4];
    const int*   pemd_sys_idx   = (const int*)d_in[5];
    // d_in[6] = precomp_sys_idx (unused by the reference computation)
    const int*   precomp_map    = (const int*)d_in[7];
    const int*   source_sys_idx = (const int*)d_in[8];
    float* out = (float*)d_out;

    int*   ws_i = (int*)d_ws;
    float* wsP  = (float*)((char*)d_ws + 1024);
    float* wsS  = (float*)((char*)d_ws + 4096);

    lens_setup<<<1, 128, 0, stream>>>(pemd_params, precomp_params, source_params,
                                      batch_idx, pemd_sys_idx, precomp_map,
                                      source_sys_idx, ws_i, wsP, wsS);

    dim3 grid(NPIX / 2048, BN, 1);  // 72 x 64 blocks, 256 thr x 8 px
    lens_main<<<grid, 256, 0, stream>>>(lens_grid, ws_i, wsP, wsS, out);
}